// Round 1
// baseline (935.406 us; speedup 1.0000x reference)
//
#include <hip/hip_runtime.h>

#define NN 50000
#define EE 1600000
#define HC 128
#define EPSV 1e-5f
#define NEGS 0.2f

static inline int cdiv(int a, int b) { return (a + b - 1) / b; }

// h0 = x @ Wn + bn   (thread per (node, channel))
__global__ __launch_bounds__(256) void k_h0(const float* __restrict__ x, const float* __restrict__ Wn,
                                            const float* __restrict__ bn, float* __restrict__ h) {
  int idx = blockIdx.x * 256 + threadIdx.x;
  if (idx >= NN * HC) return;
  int n = idx >> 7, ch = idx & 127;
  float s = bn[ch];
  const float* xr = x + n * 16;
#pragma unroll
  for (int f = 0; f < 16; ++f) s += xr[f] * Wn[f * HC + ch];
  h[idx] = s;
}

__global__ __launch_bounds__(256) void k_hist(const int* __restrict__ ei, int* __restrict__ cnt) {
  int e = blockIdx.x * 256 + threadIdx.x;
  if (e < EE) atomicAdd(&cnt[ei[EE + e]], 1);  // dst row
}

__global__ __launch_bounds__(1024) void k_scan1(const int* __restrict__ cnt, int* __restrict__ tmp,
                                                int* __restrict__ bsum) {
  __shared__ int lds[1024];
  int t = threadIdx.x;
  int i = blockIdx.x * 1024 + t;
  int v = (i < NN) ? cnt[i] : 0;
  lds[t] = v;
  __syncthreads();
  for (int off = 1; off < 1024; off <<= 1) {
    int u = (t >= off) ? lds[t - off] : 0;
    __syncthreads();
    lds[t] += u;
    __syncthreads();
  }
  if (i < NN) tmp[i] = lds[t] - v;  // exclusive within block
  if (t == 1023) bsum[blockIdx.x] = lds[1023];
}

__global__ void k_scan2(int* bsum, int nb) {
  if (threadIdx.x == 0 && blockIdx.x == 0) {
    int run = 0;
    for (int b = 0; b < nb; ++b) { int q = bsum[b]; bsum[b] = run; run += q; }
  }
}

__global__ __launch_bounds__(1024) void k_scan3(const int* __restrict__ tmp, const int* __restrict__ bsum,
                                                int* __restrict__ row_ptr, int* __restrict__ wr_ptr) {
  int t = threadIdx.x;
  int i = blockIdx.x * 1024 + t;
  if (i < NN) {
    int v = tmp[i] + bsum[blockIdx.x];
    row_ptr[i] = v;
    wr_ptr[i] = v;
  }
  if (i == 0) row_ptr[NN] = EE;
}

__global__ __launch_bounds__(256) void k_scatter(const int* __restrict__ ei, const float* __restrict__ ea,
                                                 int* __restrict__ wr_ptr, int* __restrict__ csr_src,
                                                 int* __restrict__ csr_dst, float* __restrict__ csr_attr) {
  int e = blockIdx.x * 256 + threadIdx.x;
  if (e >= EE) return;
  int s = ei[e], d = ei[EE + e];
  const float4* a = (const float4*)(ea + (size_t)e * 8);
  float4 a0 = a[0], a1 = a[1];
  int pos = atomicAdd(&wr_ptr[d], 1);
  csr_src[pos] = s;
  csr_dst[pos] = d;
  float4* o = (float4*)(csr_attr + (size_t)pos * 8);
  o[0] = a0;
  o[1] = a1;
}

// mean incoming raw edge_attr per node (wave per node; lane = 8 attrs x 8 edge-groups)
__global__ __launch_bounds__(256) void k_mean(const int* __restrict__ row_ptr, const float* __restrict__ csr_attr,
                                              float* __restrict__ mean_attr) {
  int wid = (blockIdx.x * 256 + threadIdx.x) >> 6;
  if (wid >= NN) return;
  int lane = threadIdx.x & 63;
  int j0 = row_ptr[wid], j1 = row_ptr[wid + 1];
  int f = lane & 7, g = lane >> 3;
  float s = 0.f;
  for (int j = j0 + g; j < j1; j += 8) s += csr_attr[(size_t)j * 8 + f];
  s += __shfl_xor(s, 8);
  s += __shfl_xor(s, 16);
  s += __shfl_xor(s, 32);
  if (g == 0) mean_attr[wid * 8 + f] = s / fmaxf((float)(j1 - j0), 1.f);
}

// Pc[i*36 + f*4 + h] = (We @ (W_edge[i] contracted with att_e[i]))[f,h],  Pc[i*36+32+h] = be . v_e[:,h]
__global__ __launch_bounds__(128) void k_wcoef(const float* __restrict__ We, const float* __restrict__ be,
                                               const float* __restrict__ Wed, const float* __restrict__ atte,
                                               float* __restrict__ Pc) {
  __shared__ float v[128][4];
  int t = threadIdx.x;
  for (int i = 0; i < 3; ++i) {
#pragma unroll
    for (int hh = 0; hh < 4; ++hh) {
      float s = 0.f;
      for (int hd = 0; hd < 32; ++hd)
        s += Wed[((size_t)i * 128 + t) * 128 + hh * 32 + hd] * atte[i * 128 + hh * 32 + hd];
      v[t][hh] = s;
    }
    __syncthreads();
    if (t < 32) {
      int f = t >> 2, hh = t & 3;
      float s = 0.f;
      for (int c2 = 0; c2 < 128; ++c2) s += We[f * 128 + c2] * v[c2][hh];
      Pc[i * 36 + f * 4 + hh] = s;
    }
    if (t < 4) {
      float s = 0.f;
      for (int c2 = 0; c2 < 128; ++c2) s += be[c2] * v[c2][t];
      Pc[i * 36 + 32 + t] = s;
    }
    __syncthreads();
  }
}

// Fused: x_in = LN(h); xs = x_in @ Wg; a_src/a_dst head dots. 64 nodes/block, 256 threads.
__global__ __launch_bounds__(256) void k_node(const float* __restrict__ h, const float* __restrict__ lng,
                                              const float* __restrict__ lnb, const float* __restrict__ Wg,
                                              const float* __restrict__ atts, const float* __restrict__ attd,
                                              float* __restrict__ xs, float* __restrict__ asrc,
                                              float* __restrict__ adst) {
  __shared__ float hx[64][132];
  __shared__ float wg[32][132];
  int t = threadIdx.x;
  int n0 = blockIdx.x * 64;
  {
    int row = t >> 2, q = t & 3;  // 4 threads per node row, 32 cols each
    int n = n0 + row;
    float vals[32];
    if (n < NN) {
      const float* hr = h + (size_t)n * HC + q * 32;
#pragma unroll
      for (int j = 0; j < 32; j += 4) {
        float4 vv = *(const float4*)(hr + j);
        vals[j] = vv.x; vals[j + 1] = vv.y; vals[j + 2] = vv.z; vals[j + 3] = vv.w;
      }
    } else {
#pragma unroll
      for (int j = 0; j < 32; ++j) vals[j] = 0.f;
    }
    float sum = 0.f;
#pragma unroll
    for (int j = 0; j < 32; ++j) sum += vals[j];
    sum += __shfl_xor(sum, 1);
    sum += __shfl_xor(sum, 2);
    float mu = sum * (1.f / 128.f);
    float sq = 0.f;
#pragma unroll
    for (int j = 0; j < 32; ++j) { float dmu = vals[j] - mu; sq += dmu * dmu; }
    sq += __shfl_xor(sq, 1);
    sq += __shfl_xor(sq, 2);
    float rs = rsqrtf(sq * (1.f / 128.f) + EPSV);
#pragma unroll
    for (int j = 0; j < 32; ++j) {
      int ch = q * 32 + j;
      hx[row][ch] = (vals[j] - mu) * rs * lng[ch] + lnb[ch];
    }
  }
  __syncthreads();
  int tx = t & 63, ty = t >> 6;
  int ch0 = 2 * tx, ch1 = ch0 + 1;
  float acc0[16], acc1[16];
#pragma unroll
  for (int nn = 0; nn < 16; ++nn) { acc0[nn] = 0.f; acc1[nn] = 0.f; }
  for (int k0 = 0; k0 < 128; k0 += 32) {
    {
      int r = t >> 3, cb = (t & 7) * 16;
      const float* src = Wg + (size_t)(k0 + r) * HC + cb;
      float4 v0 = *(const float4*)(src);
      float4 v1 = *(const float4*)(src + 4);
      float4 v2 = *(const float4*)(src + 8);
      float4 v3 = *(const float4*)(src + 12);
      *(float4*)&wg[r][cb] = v0;
      *(float4*)&wg[r][cb + 4] = v1;
      *(float4*)&wg[r][cb + 8] = v2;
      *(float4*)&wg[r][cb + 12] = v3;
    }
    __syncthreads();
#pragma unroll
    for (int kq = 0; kq < 32; kq += 4) {
      float w00 = wg[kq + 0][ch0], w01 = wg[kq + 0][ch1];
      float w10 = wg[kq + 1][ch0], w11 = wg[kq + 1][ch1];
      float w20 = wg[kq + 2][ch0], w21 = wg[kq + 2][ch1];
      float w30 = wg[kq + 3][ch0], w31 = wg[kq + 3][ch1];
#pragma unroll
      for (int nn = 0; nn < 16; ++nn) {
        float4 xv = *(const float4*)&hx[ty * 16 + nn][k0 + kq];
        acc0[nn] += xv.x * w00 + xv.y * w10 + xv.z * w20 + xv.w * w30;
        acc1[nn] += xv.x * w01 + xv.y * w11 + xv.z * w21 + xv.w * w31;
      }
    }
    __syncthreads();
  }
  float as0 = atts[ch0], as1 = atts[ch1];
  float ad0 = attd[ch0], ad1 = attd[ch1];
  int head = tx >> 4;
#pragma unroll
  for (int nn = 0; nn < 16; ++nn) {
    int n = n0 + ty * 16 + nn;
    float ap = acc0[nn] * as0 + acc1[nn] * as1;
    float dp = acc0[nn] * ad0 + acc1[nn] * ad1;
    ap += __shfl_xor(ap, 1); ap += __shfl_xor(ap, 2); ap += __shfl_xor(ap, 4); ap += __shfl_xor(ap, 8);
    dp += __shfl_xor(dp, 1); dp += __shfl_xor(dp, 2); dp += __shfl_xor(dp, 4); dp += __shfl_xor(dp, 8);
    if (n < NN) {
      if ((tx & 15) == 0) {
        asrc[n * 4 + head] = ap;
        adst[n * 4 + head] = dp;
      }
      float2 o;
      o.x = acc0[nn];
      o.y = acc1[nn];
      *(float2*)(xs + (size_t)n * HC + ch0) = o;
    }
  }
}

// per-edge unnormalized attention weights ex[j][4] (CSR order; no max-subtraction, logits << 1)
__global__ __launch_bounds__(256) void k_score(const int* __restrict__ csr_src, const int* __restrict__ csr_dst,
                                               const float* __restrict__ csr_attr, const float* __restrict__ asrc,
                                               const float* __restrict__ adst, const float* __restrict__ Pc,
                                               float* __restrict__ ex4) {
  __shared__ float P[36];
  if (threadIdx.x < 36) P[threadIdx.x] = Pc[threadIdx.x];
  __syncthreads();
  int j = blockIdx.x * 256 + threadIdx.x;
  if (j >= EE) return;
  int s = csr_src[j], d = csr_dst[j];
  const float* ar = csr_attr + (size_t)j * 8;
  float4 q0 = *(const float4*)ar;
  float4 q1 = *(const float4*)(ar + 4);
  float4 as = *(const float4*)(asrc + (size_t)s * 4);
  float4 ad = *(const float4*)(adst + (size_t)d * 4);
  float4 e;
  {
    float se = P[32] + q0.x * P[0] + q0.y * P[4] + q0.z * P[8] + q0.w * P[12] + q1.x * P[16] + q1.y * P[20] +
               q1.z * P[24] + q1.w * P[28];
    float al = as.x + ad.x + se;
    al = al > 0.f ? al : NEGS * al;
    e.x = __expf(al);
  }
  {
    float se = P[33] + q0.x * P[1] + q0.y * P[5] + q0.z * P[9] + q0.w * P[13] + q1.x * P[17] + q1.y * P[21] +
               q1.z * P[25] + q1.w * P[29];
    float al = as.y + ad.y + se;
    al = al > 0.f ? al : NEGS * al;
    e.y = __expf(al);
  }
  {
    float se = P[34] + q0.x * P[2] + q0.y * P[6] + q0.z * P[10] + q0.w * P[14] + q1.x * P[18] + q1.y * P[22] +
               q1.z * P[26] + q1.w * P[30];
    float al = as.z + ad.z + se;
    al = al > 0.f ? al : NEGS * al;
    e.z = __expf(al);
  }
  {
    float se = P[35] + q0.x * P[3] + q0.y * P[7] + q0.z * P[11] + q0.w * P[15] + q1.x * P[19] + q1.y * P[23] +
               q1.z * P[27] + q1.w * P[31];
    float al = as.w + ad.w + se;
    al = al > 0.f ? al : NEGS * al;
    e.w = __expf(al);
  }
  *(float4*)(ex4 + (size_t)j * 4) = e;
}

// wave per node: register-accumulate Sum(ex*xs[src]) and Sum(ex); add self-loop; divide; h += relu(out+bg)
__global__ __launch_bounds__(256) void k_aggr(const int* __restrict__ row_ptr, const int* __restrict__ csr_src,
                                              const float* __restrict__ ex4, const float* __restrict__ xs,
                                              const float* __restrict__ asrc, const float* __restrict__ adst,
                                              const float* __restrict__ mean_attr, const float* __restrict__ Pc,
                                              const float* __restrict__ bgi, float* __restrict__ h) {
  int wid = (blockIdx.x * 256 + threadIdx.x) >> 6;
  if (wid >= NN) return;
  int lane = threadIdx.x & 63;
  int ch0 = 2 * lane, ch1 = ch0 + 1, head = lane >> 4;
  int j0 = row_ptr[wid], j1 = row_ptr[wid + 1];
  float acc0 = 0.f, acc1 = 0.f, dsum = 0.f;
  int j = j0;
  for (; j + 4 <= j1; j += 4) {
    int s0 = csr_src[j], s1 = csr_src[j + 1], s2 = csr_src[j + 2], s3 = csr_src[j + 3];
    float e0 = ex4[(size_t)(j + 0) * 4 + head];
    float e1 = ex4[(size_t)(j + 1) * 4 + head];
    float e2 = ex4[(size_t)(j + 2) * 4 + head];
    float e3 = ex4[(size_t)(j + 3) * 4 + head];
    float2 x0 = *(const float2*)(xs + (size_t)s0 * HC + ch0);
    float2 x1 = *(const float2*)(xs + (size_t)s1 * HC + ch0);
    float2 x2 = *(const float2*)(xs + (size_t)s2 * HC + ch0);
    float2 x3 = *(const float2*)(xs + (size_t)s3 * HC + ch0);
    acc0 += e0 * x0.x + e1 * x1.x + e2 * x2.x + e3 * x3.x;
    acc1 += e0 * x0.y + e1 * x1.y + e2 * x2.y + e3 * x3.y;
    dsum += e0 + e1 + e2 + e3;
  }
  for (; j < j1; ++j) {
    int s0 = csr_src[j];
    float e0 = ex4[(size_t)j * 4 + head];
    float2 x0 = *(const float2*)(xs + (size_t)s0 * HC + ch0);
    acc0 += e0 * x0.x;
    acc1 += e0 * x0.y;
    dsum += e0;
  }
  float av = asrc[wid * 4 + head] + adst[wid * 4 + head];
  float al = 0.f;
  if (j1 > j0) {
    al = Pc[32 + head];
#pragma unroll
    for (int f = 0; f < 8; ++f) al += mean_attr[wid * 8 + f] * Pc[f * 4 + head];
  }
  float alpha = av + al;
  alpha = alpha > 0.f ? alpha : NEGS * alpha;
  float exl = __expf(alpha);
  float2 xself = *(const float2*)(xs + (size_t)wid * HC + ch0);
  float inv = 1.f / (dsum + exl);
  float o0 = (acc0 + exl * xself.x) * inv;
  float o1 = (acc1 + exl * xself.y) * inv;
  float* hp = h + (size_t)wid * HC;
  hp[ch0] += fmaxf(0.f, o0 + bgi[ch0]);
  hp[ch1] += fmaxf(0.f, o1 + bgi[ch1]);
}

__global__ __launch_bounds__(256) void k_emb(const float* __restrict__ h, float* __restrict__ emb) {
  int t = blockIdx.x * 256 + threadIdx.x;
  int stride = gridDim.x * 256;  // multiple of 128 -> fixed channel per thread
  float s = 0.f;
  for (int i = t; i < NN * HC; i += stride) s += h[i];
  __shared__ float red[256];
  red[threadIdx.x] = s;
  __syncthreads();
  if (threadIdx.x < 128) {
    float v2 = red[threadIdx.x] + red[threadIdx.x + 128];
    atomicAdd(&emb[threadIdx.x], v2 * (1.f / NN));
  }
}

extern "C" void kernel_launch(void* const* d_in, const int* in_sizes, int n_in, void* d_out, int out_size,
                              void* d_ws, size_t ws_size, hipStream_t stream) {
  (void)in_sizes; (void)n_in; (void)out_size; (void)ws_size;
  const float* x = (const float*)d_in[0];
  const int* ei = (const int*)d_in[1];
  const float* ea = (const float*)d_in[2];
  const float* Wn = (const float*)d_in[3];
  const float* bn = (const float*)d_in[4];
  const float* We = (const float*)d_in[5];
  const float* be = (const float*)d_in[6];
  const float* lng = (const float*)d_in[7];
  const float* lnb = (const float*)d_in[8];
  const float* Wg = (const float*)d_in[9];
  const float* atts = (const float*)d_in[10];
  const float* attd = (const float*)d_in[11];
  const float* atte = (const float*)d_in[12];
  const float* Wed = (const float*)d_in[13];
  const float* bg = (const float*)d_in[14];
  float* h = (float*)d_out;                 // [N,128]
  float* emb = h + (size_t)NN * HC;         // [128]

  char* w = (char*)d_ws;
  size_t off = 0;
  auto alloc = [&](size_t bytes) {
    void* p = w + off;
    off = (off + bytes + 255) & ~(size_t)255;
    return p;
  };
  float* xs = (float*)alloc((size_t)NN * HC * 4);
  float* asrc = (float*)alloc((size_t)NN * 4 * 4);
  float* adst = (float*)alloc((size_t)NN * 4 * 4);
  float* meanat = (float*)alloc((size_t)NN * 8 * 4);
  int* cnt = (int*)alloc((size_t)NN * 4);
  int* row_ptr = (int*)alloc((size_t)(NN + 1) * 4);
  int* wr_ptr = (int*)alloc((size_t)NN * 4);
  int* bsum = (int*)alloc(256);
  int* stmp = (int*)alloc((size_t)NN * 4);
  int* csr_src = (int*)alloc((size_t)EE * 4);
  int* csr_dst = (int*)alloc((size_t)EE * 4);
  float* csr_attr = (float*)alloc((size_t)EE * 8 * 4);
  float* ex4b = (float*)alloc((size_t)EE * 4 * 4);
  float* Pc = (float*)alloc(3 * 36 * 4);

  hipMemsetAsync(cnt, 0, (size_t)NN * 4, stream);
  hipMemsetAsync(emb, 0, HC * 4, stream);

  k_h0<<<cdiv(NN * HC, 256), 256, 0, stream>>>(x, Wn, bn, h);
  k_hist<<<cdiv(EE, 256), 256, 0, stream>>>(ei, cnt);
  int nb = cdiv(NN, 1024);
  k_scan1<<<nb, 1024, 0, stream>>>(cnt, stmp, bsum);
  k_scan2<<<1, 64, 0, stream>>>(bsum, nb);
  k_scan3<<<nb, 1024, 0, stream>>>(stmp, bsum, row_ptr, wr_ptr);
  k_scatter<<<cdiv(EE, 256), 256, 0, stream>>>(ei, ea, wr_ptr, csr_src, csr_dst, csr_attr);
  k_mean<<<cdiv(NN, 4), 256, 0, stream>>>(row_ptr, csr_attr, meanat);
  k_wcoef<<<1, 128, 0, stream>>>(We, be, Wed, atte, Pc);

  for (int i = 0; i < 3; ++i) {
    k_node<<<cdiv(NN, 64), 256, 0, stream>>>(h, lng + i * HC, lnb + i * HC, Wg + (size_t)i * HC * HC,
                                             atts + i * HC, attd + i * HC, xs, asrc, adst);
    k_score<<<cdiv(EE, 256), 256, 0, stream>>>(csr_src, csr_dst, csr_attr, asrc, adst, Pc + i * 36, ex4b);
    k_aggr<<<cdiv(NN, 4), 256, 0, stream>>>(row_ptr, csr_src, ex4b, xs, asrc, adst, meanat, Pc + i * 36,
                                            bg + i * HC, h);
  }
  k_emb<<<512, 256, 0, stream>>>(h, emb);
}

// Round 2
// 559.049 us; speedup vs baseline: 1.6732x; 1.6732x over previous
//
#include <hip/hip_runtime.h>

#define NN 50000
#define EE 1600000
#define HC 128
#define EPSV 1e-5f
#define NEGS 0.2f

typedef __bf16 bf16x8 __attribute__((ext_vector_type(8)));
typedef __bf16 bf16x2 __attribute__((ext_vector_type(2)));
typedef float f32x4 __attribute__((ext_vector_type(4)));

static inline int cdiv(int a, int b) { return (a + b - 1) / b; }

__device__ inline float blo(unsigned v) { return __uint_as_float(v << 16); }
__device__ inline float bhi(unsigned v) { return __uint_as_float(v & 0xffff0000u); }

// h0 = x @ Wn + bn
__global__ __launch_bounds__(256) void k_h0(const float* __restrict__ x, const float* __restrict__ Wn,
                                            const float* __restrict__ bn, float* __restrict__ h) {
  int idx = blockIdx.x * 256 + threadIdx.x;
  if (idx >= NN * HC) return;
  int n = idx >> 7, ch = idx & 127;
  float s = bn[ch];
  const float* xr = x + n * 16;
#pragma unroll
  for (int f = 0; f < 16; ++f) s += xr[f] * Wn[f * HC + ch];
  h[idx] = s;
}

__global__ __launch_bounds__(256) void k_hist(const int* __restrict__ ei, int* __restrict__ cnt) {
  int e = blockIdx.x * 256 + threadIdx.x;
  if (e < EE) atomicAdd(&cnt[ei[EE + e]], 1);
}

__global__ __launch_bounds__(1024) void k_scan1(const int* __restrict__ cnt, int* __restrict__ tmp,
                                                int* __restrict__ bsum) {
  __shared__ int lds[1024];
  int t = threadIdx.x;
  int i = blockIdx.x * 1024 + t;
  int v = (i < NN) ? cnt[i] : 0;
  lds[t] = v;
  __syncthreads();
  for (int off = 1; off < 1024; off <<= 1) {
    int u = (t >= off) ? lds[t - off] : 0;
    __syncthreads();
    lds[t] += u;
    __syncthreads();
  }
  if (i < NN) tmp[i] = lds[t] - v;
  if (t == 1023) bsum[blockIdx.x] = lds[1023];
}

__global__ void k_scan2(int* bsum, int nb) {
  if (threadIdx.x == 0 && blockIdx.x == 0) {
    int run = 0;
    for (int b = 0; b < nb; ++b) { int q = bsum[b]; bsum[b] = run; run += q; }
  }
}

__global__ __launch_bounds__(1024) void k_scan3(const int* __restrict__ tmp, const int* __restrict__ bsum,
                                                int* __restrict__ row_ptr, int* __restrict__ wr_ptr) {
  int t = threadIdx.x;
  int i = blockIdx.x * 1024 + t;
  if (i < NN) {
    int v = tmp[i] + bsum[blockIdx.x];
    row_ptr[i] = v;
    wr_ptr[i] = v;
  }
  if (i == 0) row_ptr[NN] = EE;
}

// Pc[i*36 + f*4 + h] = (We @ (W_edge[i] . att_e[i]))[f,h],  Pc[i*36+32+h] = be . v_e[:,h]
__global__ __launch_bounds__(128) void k_wcoef(const float* __restrict__ We, const float* __restrict__ be,
                                               const float* __restrict__ Wed, const float* __restrict__ atte,
                                               float* __restrict__ Pc) {
  __shared__ float v[128][4];
  int t = threadIdx.x;
  for (int i = 0; i < 3; ++i) {
#pragma unroll
    for (int hh = 0; hh < 4; ++hh) {
      float s = 0.f;
      for (int hd = 0; hd < 32; ++hd)
        s += Wed[((size_t)i * 128 + t) * 128 + hh * 32 + hd] * atte[i * 128 + hh * 32 + hd];
      v[t][hh] = s;
    }
    __syncthreads();
    if (t < 32) {
      int f = t >> 2, hh = t & 3;
      float s = 0.f;
      for (int c2 = 0; c2 < 128; ++c2) s += We[f * 128 + c2] * v[c2][hh];
      Pc[i * 36 + f * 4 + hh] = s;
    }
    if (t < 4) {
      float s = 0.f;
      for (int c2 = 0; c2 < 128; ++c2) s += be[c2] * v[c2][t];
      Pc[i * 36 + 32 + t] = s;
    }
    __syncthreads();
  }
}

// WgT padded bf16: wgt[i][n][kp] (kp stride 136) = Wg[i][kp][n]
__global__ __launch_bounds__(256) void k_prep(const float* __restrict__ Wg, __bf16* __restrict__ wgt) {
  int idx = blockIdx.x * 256 + threadIdx.x;
  if (idx >= 3 * 128 * 136) return;
  int i = idx / (128 * 136);
  int rem = idx - i * 128 * 136;
  int n = rem / 136, kp = rem - n * 136;
  float v = (kp < 128) ? Wg[(size_t)i * 16384 + kp * 128 + n] : 0.f;
  wgt[idx] = (__bf16)v;
}

// CSR build fused with per-edge a_edge precompute for all 3 layers.
__global__ __launch_bounds__(256) void k_build(const int* __restrict__ ei, const float* __restrict__ ea,
                                               const float* __restrict__ Pc, int* __restrict__ wr_ptr,
                                               int* __restrict__ csr_src, float* __restrict__ ae0,
                                               float* __restrict__ ae1, float* __restrict__ ae2) {
  __shared__ float P[108];
  if (threadIdx.x < 108) P[threadIdx.x] = Pc[threadIdx.x];
  __syncthreads();
  int e = blockIdx.x * 256 + threadIdx.x;
  if (e >= EE) return;
  int s = ei[e], d = ei[EE + e];
  const float* ar = ea + (size_t)e * 8;
  float4 q0 = *(const float4*)ar;
  float4 q1 = *(const float4*)(ar + 4);
  float a[8] = {q0.x, q0.y, q0.z, q0.w, q1.x, q1.y, q1.z, q1.w};
  float4 v[3];
#pragma unroll
  for (int i = 0; i < 3; ++i) {
    const float* p = P + i * 36;
    float r[4];
#pragma unroll
    for (int hh = 0; hh < 4; ++hh) {
      float s2 = p[32 + hh];
#pragma unroll
      for (int f = 0; f < 8; ++f) s2 += a[f] * p[f * 4 + hh];
      r[hh] = s2;
    }
    v[i] = make_float4(r[0], r[1], r[2], r[3]);
  }
  int pos = atomicAdd(&wr_ptr[d], 1);
  csr_src[pos] = s;
  *(float4*)(ae0 + (size_t)pos * 4) = v[0];
  *(float4*)(ae1 + (size_t)pos * 4) = v[1];
  *(float4*)(ae2 + (size_t)pos * 4) = v[2];
}

// Fused LN + bf16 MFMA GEMM: xs = LN(h) @ Wg  (64 nodes/block, 4 waves, N=128 full)
__global__ __launch_bounds__(256) void k_node(const float* __restrict__ h, const float* __restrict__ lng,
                                              const float* __restrict__ lnb, const __bf16* __restrict__ wgt,
                                              __bf16* __restrict__ xsb) {
  __shared__ __bf16 sA[64][136];
  __shared__ __bf16 sB[128][136];
  int t = threadIdx.x;
  int n0 = blockIdx.x * 64;
  // stage WgT (padded, 34816 B) linearly
  {
    char* wdst = (char*)&sB[0][0];
    const char* wsrc = (const char*)wgt;
    for (int off = t * 16; off < 34816; off += 4096)
      *(uint4*)(wdst + off) = *(const uint4*)(wsrc + off);
  }
  // LN into sA (bf16)
  {
    int row = t >> 2, q = t & 3;
    int n = n0 + row;
    float vals[32];
    if (n < NN) {
      const float* hr = h + (size_t)n * HC + q * 32;
#pragma unroll
      for (int j = 0; j < 32; j += 4) {
        float4 vv = *(const float4*)(hr + j);
        vals[j] = vv.x; vals[j + 1] = vv.y; vals[j + 2] = vv.z; vals[j + 3] = vv.w;
      }
    } else {
#pragma unroll
      for (int j = 0; j < 32; ++j) vals[j] = 0.f;
    }
    float sum = 0.f;
#pragma unroll
    for (int j = 0; j < 32; ++j) sum += vals[j];
    sum += __shfl_xor(sum, 1);
    sum += __shfl_xor(sum, 2);
    float mu = sum * (1.f / 128.f);
    float sq = 0.f;
#pragma unroll
    for (int j = 0; j < 32; ++j) { float dmu = vals[j] - mu; sq += dmu * dmu; }
    sq += __shfl_xor(sq, 1);
    sq += __shfl_xor(sq, 2);
    float rs = rsqrtf(sq * (1.f / 128.f) + EPSV);
#pragma unroll
    for (int j = 0; j < 32; j += 2) {
      int ch = q * 32 + j;
      float v0 = (vals[j] - mu) * rs * lng[ch] + lnb[ch];
      float v1 = (vals[j + 1] - mu) * rs * lng[ch + 1] + lnb[ch + 1];
      bf16x2 p;
      p.x = (__bf16)v0;
      p.y = (__bf16)v1;
      *(bf16x2*)&sA[row][ch] = p;
    }
  }
  __syncthreads();
  // MFMA: wave w -> rows [w*16, w*16+16), all 8 n-tiles
  int lane = t & 63;
  int c15 = lane & 15, g = lane >> 4;
  int m0 = (t >> 6) * 16;
  f32x4 acc[8];
#pragma unroll
  for (int nt = 0; nt < 8; ++nt) acc[nt] = (f32x4){0.f, 0.f, 0.f, 0.f};
#pragma unroll
  for (int ks = 0; ks < 4; ++ks) {
    bf16x8 av = *(const bf16x8*)&sA[m0 + c15][ks * 32 + g * 8];
#pragma unroll
    for (int nt = 0; nt < 8; ++nt) {
      bf16x8 bv = *(const bf16x8*)&sB[nt * 16 + c15][ks * 32 + g * 8];
      acc[nt] = __builtin_amdgcn_mfma_f32_16x16x32_bf16(av, bv, acc[nt], 0, 0, 0);
    }
  }
  // store xs bf16: C layout col=lane&15, row=(lane>>4)*4+reg
  int nbase = n0 + m0 + g * 4;
#pragma unroll
  for (int r = 0; r < 4; ++r) {
    int n = nbase + r;
    if (n < NN) {
      __bf16* op = xsb + (size_t)n * HC + c15;
#pragma unroll
      for (int nt = 0; nt < 8; ++nt) op[nt * 16] = (__bf16)acc[nt][r];
    }
  }
}

// attention head dots from xs (bf16): thread per (node, head)
__global__ __launch_bounds__(256) void k_adots(const __bf16* __restrict__ xsb, const float* __restrict__ atts,
                                               const float* __restrict__ attd, float* __restrict__ asrc,
                                               float* __restrict__ adst) {
  __shared__ float ss[128], sd[128];
  if (threadIdx.x < 128) {
    ss[threadIdx.x] = atts[threadIdx.x];
    sd[threadIdx.x] = attd[threadIdx.x];
  }
  __syncthreads();
  int idx = blockIdx.x * 256 + threadIdx.x;
  if (idx >= NN * 4) return;
  int n = idx >> 2, hh = idx & 3;
  const unsigned* p = (const unsigned*)(xsb + (size_t)n * HC + hh * 32);
  float s = 0.f, d = 0.f;
#pragma unroll
  for (int q = 0; q < 16; ++q) {
    unsigned v = p[q];
    float lo = blo(v), hi = bhi(v);
    int ch = hh * 32 + q * 2;
    s += lo * ss[ch] + hi * ss[ch + 1];
    d += lo * sd[ch] + hi * sd[ch + 1];
  }
  asrc[idx] = s;
  adst[idx] = d;
}

// wave per node: fused score (leaky+exp) + aggregation + self-loop + residual relu
__global__ __launch_bounds__(256) void k_aggr(const int* __restrict__ row_ptr, const int* __restrict__ csr_src,
                                              const float* __restrict__ aep, const __bf16* __restrict__ xsb,
                                              const float* __restrict__ asrc, const float* __restrict__ adst,
                                              const float* __restrict__ bgi, float* __restrict__ h) {
  int wid = (blockIdx.x * 256 + threadIdx.x) >> 6;
  if (wid >= NN) return;
  int lane = threadIdx.x & 63;
  int ch0 = 2 * lane, head = lane >> 4;
  int j0 = row_ptr[wid], j1 = row_ptr[wid + 1];
  float ad = adst[wid * 4 + head];
  float acc0 = 0.f, acc1 = 0.f, dsum = 0.f, aes = 0.f;
  int j = j0;
  for (; j + 4 <= j1; j += 4) {
    int s0 = csr_src[j], s1 = csr_src[j + 1], s2 = csr_src[j + 2], s3 = csr_src[j + 3];
    float v0 = aep[(size_t)(j + 0) * 4 + head];
    float v1 = aep[(size_t)(j + 1) * 4 + head];
    float v2 = aep[(size_t)(j + 2) * 4 + head];
    float v3 = aep[(size_t)(j + 3) * 4 + head];
    float as0 = asrc[(size_t)s0 * 4 + head];
    float as1 = asrc[(size_t)s1 * 4 + head];
    float as2 = asrc[(size_t)s2 * 4 + head];
    float as3 = asrc[(size_t)s3 * 4 + head];
    unsigned x0 = *(const unsigned*)(xsb + (size_t)s0 * HC + ch0);
    unsigned x1 = *(const unsigned*)(xsb + (size_t)s1 * HC + ch0);
    unsigned x2 = *(const unsigned*)(xsb + (size_t)s2 * HC + ch0);
    unsigned x3 = *(const unsigned*)(xsb + (size_t)s3 * HC + ch0);
    float a0 = as0 + ad + v0; a0 = a0 > 0.f ? a0 : NEGS * a0;
    float a1 = as1 + ad + v1; a1 = a1 > 0.f ? a1 : NEGS * a1;
    float a2 = as2 + ad + v2; a2 = a2 > 0.f ? a2 : NEGS * a2;
    float a3 = as3 + ad + v3; a3 = a3 > 0.f ? a3 : NEGS * a3;
    float e0 = __expf(a0), e1 = __expf(a1), e2 = __expf(a2), e3 = __expf(a3);
    acc0 += e0 * blo(x0) + e1 * blo(x1) + e2 * blo(x2) + e3 * blo(x3);
    acc1 += e0 * bhi(x0) + e1 * bhi(x1) + e2 * bhi(x2) + e3 * bhi(x3);
    dsum += e0 + e1 + e2 + e3;
    aes += v0 + v1 + v2 + v3;
  }
  for (; j < j1; ++j) {
    int s0 = csr_src[j];
    float v0 = aep[(size_t)j * 4 + head];
    float as0 = asrc[(size_t)s0 * 4 + head];
    unsigned x0 = *(const unsigned*)(xsb + (size_t)s0 * HC + ch0);
    float a0 = as0 + ad + v0; a0 = a0 > 0.f ? a0 : NEGS * a0;
    float e0 = __expf(a0);
    acc0 += e0 * blo(x0);
    acc1 += e0 * bhi(x0);
    dsum += e0;
    aes += v0;
  }
  int deg = j1 - j0;
  float aself = (deg > 0) ? aes / (float)deg : 0.f;
  float al = asrc[wid * 4 + head] + ad + aself;
  al = al > 0.f ? al : NEGS * al;
  float exl = __expf(al);
  unsigned xv = *(const unsigned*)(xsb + (size_t)wid * HC + ch0);
  float inv = 1.f / (dsum + exl);
  float o0 = (acc0 + exl * blo(xv)) * inv;
  float o1 = (acc1 + exl * bhi(xv)) * inv;
  float* hp = h + (size_t)wid * HC;
  hp[ch0] += fmaxf(0.f, o0 + bgi[ch0]);
  hp[ch0 + 1] += fmaxf(0.f, o1 + bgi[ch0 + 1]);
}

__global__ __launch_bounds__(256) void k_emb(const float* __restrict__ h, float* __restrict__ emb) {
  int t = blockIdx.x * 256 + threadIdx.x;
  int stride = gridDim.x * 256;
  float s = 0.f;
  for (int i = t; i < NN * HC; i += stride) s += h[i];
  __shared__ float red[256];
  red[threadIdx.x] = s;
  __syncthreads();
  if (threadIdx.x < 128) {
    float v2 = red[threadIdx.x] + red[threadIdx.x + 128];
    atomicAdd(&emb[threadIdx.x], v2 * (1.f / NN));
  }
}

extern "C" void kernel_launch(void* const* d_in, const int* in_sizes, int n_in, void* d_out, int out_size,
                              void* d_ws, size_t ws_size, hipStream_t stream) {
  (void)in_sizes; (void)n_in; (void)out_size; (void)ws_size;
  const float* x = (const float*)d_in[0];
  const int* ei = (const int*)d_in[1];
  const float* ea = (const float*)d_in[2];
  const float* Wn = (const float*)d_in[3];
  const float* bn = (const float*)d_in[4];
  const float* We = (const float*)d_in[5];
  const float* be = (const float*)d_in[6];
  const float* lng = (const float*)d_in[7];
  const float* lnb = (const float*)d_in[8];
  const float* Wg = (const float*)d_in[9];
  const float* atts = (const float*)d_in[10];
  const float* attd = (const float*)d_in[11];
  const float* atte = (const float*)d_in[12];
  const float* Wed = (const float*)d_in[13];
  const float* bg = (const float*)d_in[14];
  float* h = (float*)d_out;
  float* emb = h + (size_t)NN * HC;

  char* w = (char*)d_ws;
  size_t off = 0;
  auto alloc = [&](size_t bytes) {
    void* p = w + off;
    off = (off + bytes + 255) & ~(size_t)255;
    return p;
  };
  __bf16* xsb = (__bf16*)alloc((size_t)NN * HC * 2);
  float* asrc = (float*)alloc((size_t)NN * 4 * 4);
  float* adst = (float*)alloc((size_t)NN * 4 * 4);
  int* cnt = (int*)alloc((size_t)NN * 4);
  int* row_ptr = (int*)alloc((size_t)(NN + 1) * 4);
  int* wr_ptr = (int*)alloc((size_t)NN * 4);
  int* bsum = (int*)alloc(256);
  int* stmp = (int*)alloc((size_t)NN * 4);
  int* csr_src = (int*)alloc((size_t)EE * 4);
  float* ae0 = (float*)alloc((size_t)EE * 4 * 4);
  float* ae1 = (float*)alloc((size_t)EE * 4 * 4);
  float* ae2 = (float*)alloc((size_t)EE * 4 * 4);
  float* Pc = (float*)alloc(3 * 36 * 4);
  __bf16* wgt = (__bf16*)alloc((size_t)3 * 128 * 136 * 2);
  float* aeplanes[3] = {ae0, ae1, ae2};

  hipMemsetAsync(cnt, 0, (size_t)NN * 4, stream);
  hipMemsetAsync(emb, 0, HC * 4, stream);

  k_h0<<<cdiv(NN * HC, 256), 256, 0, stream>>>(x, Wn, bn, h);
  k_hist<<<cdiv(EE, 256), 256, 0, stream>>>(ei, cnt);
  int nb = cdiv(NN, 1024);
  k_scan1<<<nb, 1024, 0, stream>>>(cnt, stmp, bsum);
  k_scan2<<<1, 64, 0, stream>>>(bsum, nb);
  k_scan3<<<nb, 1024, 0, stream>>>(stmp, bsum, row_ptr, wr_ptr);
  k_wcoef<<<1, 128, 0, stream>>>(We, be, Wed, atte, Pc);
  k_prep<<<cdiv(3 * 128 * 136, 256), 256, 0, stream>>>(Wg, wgt);
  k_build<<<cdiv(EE, 256), 256, 0, stream>>>(ei, ea, Pc, wr_ptr, csr_src, ae0, ae1, ae2);

  for (int i = 0; i < 3; ++i) {
    k_node<<<cdiv(NN, 64), 256, 0, stream>>>(h, lng + i * HC, lnb + i * HC, wgt + (size_t)i * 128 * 136, xsb);
    k_adots<<<cdiv(NN * 4, 256), 256, 0, stream>>>(xsb, atts + i * HC, attd + i * HC, asrc, adst);
    k_aggr<<<cdiv(NN, 4), 256, 0, stream>>>(row_ptr, csr_src, aeplanes[i], xsb, asrc, adst, bg + i * HC, h);
  }
  k_emb<<<512, 256, 0, stream>>>(h, emb);
}

// Round 3
// 548.749 us; speedup vs baseline: 1.7046x; 1.0188x over previous
//
#include <hip/hip_runtime.h>

#define NN 50000
#define EE 1600000
#define HC 128
#define EPSV 1e-5f
#define NEGS 0.2f

typedef __bf16 bf16x8 __attribute__((ext_vector_type(8)));
typedef __bf16 bf16x2 __attribute__((ext_vector_type(2)));
typedef float f32x4 __attribute__((ext_vector_type(4)));

static inline int cdiv(int a, int b) { return (a + b - 1) / b; }

__device__ inline float blo(unsigned v) { return __uint_as_float(v << 16); }
__device__ inline float bhi(unsigned v) { return __uint_as_float(v & 0xffff0000u); }
__device__ inline unsigned pkbf(float a, float b) {
  bf16x2 p;
  p.x = (__bf16)a;
  p.y = (__bf16)b;
  return *reinterpret_cast<unsigned*>(&p);
}

// h0 = x @ Wn + bn
__global__ __launch_bounds__(256) void k_h0(const float* __restrict__ x, const float* __restrict__ Wn,
                                            const float* __restrict__ bn, float* __restrict__ h) {
  int idx = blockIdx.x * 256 + threadIdx.x;
  if (idx >= NN * HC) return;
  int n = idx >> 7, ch = idx & 127;
  float s = bn[ch];
  const float* xr = x + n * 16;
#pragma unroll
  for (int f = 0; f < 16; ++f) s += xr[f] * Wn[f * HC + ch];
  h[idx] = s;
}

__global__ __launch_bounds__(256) void k_hist(const int* __restrict__ ei, int* __restrict__ cnt) {
  int e = blockIdx.x * 256 + threadIdx.x;
  if (e < EE) atomicAdd(&cnt[ei[EE + e]], 1);
}

__global__ __launch_bounds__(1024) void k_scan1(const int* __restrict__ cnt, int* __restrict__ tmp,
                                                int* __restrict__ bsum) {
  __shared__ int lds[1024];
  int t = threadIdx.x;
  int i = blockIdx.x * 1024 + t;
  int v = (i < NN) ? cnt[i] : 0;
  lds[t] = v;
  __syncthreads();
  for (int off = 1; off < 1024; off <<= 1) {
    int u = (t >= off) ? lds[t - off] : 0;
    __syncthreads();
    lds[t] += u;
    __syncthreads();
  }
  if (i < NN) tmp[i] = lds[t] - v;
  if (t == 1023) bsum[blockIdx.x] = lds[1023];
}

__global__ void k_scan2(int* bsum, int nb) {
  if (threadIdx.x == 0 && blockIdx.x == 0) {
    int run = 0;
    for (int b = 0; b < nb; ++b) { int q = bsum[b]; bsum[b] = run; run += q; }
  }
}

__global__ __launch_bounds__(1024) void k_scan3(const int* __restrict__ tmp, const int* __restrict__ bsum,
                                                int* __restrict__ row_ptr, int* __restrict__ wr_ptr) {
  int t = threadIdx.x;
  int i = blockIdx.x * 1024 + t;
  if (i < NN) {
    int v = tmp[i] + bsum[blockIdx.x];
    row_ptr[i] = v;
    wr_ptr[i] = v;
  }
  if (i == 0) row_ptr[NN] = EE;
}

// Pc[i*36 + f*4 + h] = (We @ (W_edge[i] . att_e[i]))[f,h],  Pc[i*36+32+h] = be . v_e[:,h]
__global__ __launch_bounds__(128) void k_wcoef(const float* __restrict__ We, const float* __restrict__ be,
                                               const float* __restrict__ Wed, const float* __restrict__ atte,
                                               float* __restrict__ Pc) {
  __shared__ float v[128][4];
  int t = threadIdx.x;
  for (int i = 0; i < 3; ++i) {
#pragma unroll
    for (int hh = 0; hh < 4; ++hh) {
      float s = 0.f;
      for (int hd = 0; hd < 32; ++hd)
        s += Wed[((size_t)i * 128 + t) * 128 + hh * 32 + hd] * atte[i * 128 + hh * 32 + hd];
      v[t][hh] = s;
    }
    __syncthreads();
    if (t < 32) {
      int f = t >> 2, hh = t & 3;
      float s = 0.f;
      for (int c2 = 0; c2 < 128; ++c2) s += We[f * 128 + c2] * v[c2][hh];
      Pc[i * 36 + f * 4 + hh] = s;
    }
    if (t < 4) {
      float s = 0.f;
      for (int c2 = 0; c2 < 128; ++c2) s += be[c2] * v[c2][t];
      Pc[i * 36 + 32 + t] = s;
    }
    __syncthreads();
  }
}

// WgT padded bf16: wgt[i][n][kp] (kp stride 136) = Wg[i][kp][n]
__global__ __launch_bounds__(256) void k_prep(const float* __restrict__ Wg, __bf16* __restrict__ wgt) {
  int idx = blockIdx.x * 256 + threadIdx.x;
  if (idx >= 3 * 128 * 136) return;
  int i = idx / (128 * 136);
  int rem = idx - i * 128 * 136;
  int n = rem / 136, kp = rem - n * 136;
  float v = (kp < 128) ? Wg[(size_t)i * 16384 + kp * 128 + n] : 0.f;
  wgt[idx] = (__bf16)v;
}

// CSR build: single 32B record per edge = {src, ae[l0][h01], ae[l0][h23], ae[l1][h01], ae[l1][h23],
//                                          ae[l2][h01], ae[l2][h23], pad} (bf16 pairs)
__global__ __launch_bounds__(256) void k_build(const int* __restrict__ ei, const float* __restrict__ ea,
                                               const float* __restrict__ Pc, int* __restrict__ wr_ptr,
                                               uint4* __restrict__ rec) {
  __shared__ float P[108];
  if (threadIdx.x < 108) P[threadIdx.x] = Pc[threadIdx.x];
  __syncthreads();
  int e = blockIdx.x * 256 + threadIdx.x;
  if (e >= EE) return;
  int s = ei[e], d = ei[EE + e];
  const float* ar = ea + (size_t)e * 8;
  float4 q0 = *(const float4*)ar;
  float4 q1 = *(const float4*)(ar + 4);
  float a[8] = {q0.x, q0.y, q0.z, q0.w, q1.x, q1.y, q1.z, q1.w};
  float r[3][4];
#pragma unroll
  for (int i = 0; i < 3; ++i) {
    const float* p = P + i * 36;
#pragma unroll
    for (int hh = 0; hh < 4; ++hh) {
      float s2 = p[32 + hh];
#pragma unroll
      for (int f = 0; f < 8; ++f) s2 += a[f] * p[f * 4 + hh];
      r[i][hh] = s2;
    }
  }
  int pos = atomicAdd(&wr_ptr[d], 1);
  uint4 r0, r1;
  r0.x = (unsigned)s;
  r0.y = pkbf(r[0][0], r[0][1]);
  r0.z = pkbf(r[0][2], r[0][3]);
  r0.w = pkbf(r[1][0], r[1][1]);
  r1.x = pkbf(r[1][2], r[1][3]);
  r1.y = pkbf(r[2][0], r[2][1]);
  r1.z = pkbf(r[2][2], r[2][3]);
  r1.w = 0;
  uint4* rp = rec + (size_t)pos * 2;
  rp[0] = r0;
  rp[1] = r1;
}

// Fused LN + bf16 MFMA GEMM + attention head dots. 128 nodes/block, 4 waves.
// B operand read directly from global (L2-resident WgT).
__global__ __launch_bounds__(256) void k_node(const float* __restrict__ h, const float* __restrict__ lng,
                                              const float* __restrict__ lnb, const __bf16* __restrict__ wgt,
                                              const float* __restrict__ atts, const float* __restrict__ attd,
                                              __bf16* __restrict__ xsb, float* __restrict__ asrc,
                                              float* __restrict__ adst) {
  __shared__ __bf16 sA[128][136];
  __shared__ float sAs[128], sAd[128];
  int t = threadIdx.x;
  int n0 = blockIdx.x * 128;
  if (t < 128) {
    sAs[t] = atts[t];
    sAd[t] = attd[t];
  }
  {
    int row = t >> 1, q = t & 1;
    int n = n0 + row;
    float vals[64];
    if (n < NN) {
      const float* hr = h + (size_t)n * HC + q * 64;
#pragma unroll
      for (int j = 0; j < 64; j += 4) {
        float4 vv = *(const float4*)(hr + j);
        vals[j] = vv.x; vals[j + 1] = vv.y; vals[j + 2] = vv.z; vals[j + 3] = vv.w;
      }
    } else {
#pragma unroll
      for (int j = 0; j < 64; ++j) vals[j] = 0.f;
    }
    float sum = 0.f;
#pragma unroll
    for (int j = 0; j < 64; ++j) sum += vals[j];
    sum += __shfl_xor(sum, 1);
    float mu = sum * (1.f / 128.f);
    float sq = 0.f;
#pragma unroll
    for (int j = 0; j < 64; ++j) { float dm = vals[j] - mu; sq += dm * dm; }
    sq += __shfl_xor(sq, 1);
    float rs = rsqrtf(sq * (1.f / 128.f) + EPSV);
    int chb = q * 64;
#pragma unroll
    for (int j = 0; j < 64; j += 2) {
      int ch = chb + j;
      bf16x2 p;
      p.x = (__bf16)((vals[j] - mu) * rs * lng[ch] + lnb[ch]);
      p.y = (__bf16)((vals[j + 1] - mu) * rs * lng[ch + 1] + lnb[ch + 1]);
      *(bf16x2*)&sA[row][ch] = p;
    }
  }
  __syncthreads();
  int lane = t & 63;
  int c15 = lane & 15, g = lane >> 4;
  int m0w = (t >> 6) * 32;
  f32x4 acc[16];
#pragma unroll
  for (int i = 0; i < 16; ++i) acc[i] = (f32x4){0.f, 0.f, 0.f, 0.f};
#pragma unroll
  for (int ks = 0; ks < 4; ++ks) {
    bf16x8 a0 = *(const bf16x8*)&sA[m0w + c15][ks * 32 + g * 8];
    bf16x8 a1 = *(const bf16x8*)&sA[m0w + 16 + c15][ks * 32 + g * 8];
#pragma unroll
    for (int nt = 0; nt < 8; ++nt) {
      bf16x8 bv = *(const bf16x8*)(wgt + (size_t)(nt * 16 + c15) * 136 + ks * 32 + g * 8);
      acc[nt] = __builtin_amdgcn_mfma_f32_16x16x32_bf16(a0, bv, acc[nt], 0, 0, 0);
      acc[8 + nt] = __builtin_amdgcn_mfma_f32_16x16x32_bf16(a1, bv, acc[8 + nt], 0, 0, 0);
    }
  }
#pragma unroll
  for (int mt = 0; mt < 2; ++mt) {
    int nbase = n0 + m0w + mt * 16 + g * 4;
#pragma unroll
    for (int r = 0; r < 4; ++r) {
      int n = nbase + r;
      float ps[4], pd[4];
#pragma unroll
      for (int hh = 0; hh < 4; ++hh) {
        float w0 = sAs[hh * 32 + c15], w1 = sAs[hh * 32 + 16 + c15];
        float d0 = sAd[hh * 32 + c15], d1 = sAd[hh * 32 + 16 + c15];
        float x0 = acc[mt * 8 + 2 * hh][r], x1 = acc[mt * 8 + 2 * hh + 1][r];
        ps[hh] = x0 * w0 + x1 * w1;
        pd[hh] = x0 * d0 + x1 * d1;
      }
#pragma unroll
      for (int m = 1; m < 16; m <<= 1) {
#pragma unroll
        for (int hh = 0; hh < 4; ++hh) {
          ps[hh] += __shfl_xor(ps[hh], m);
          pd[hh] += __shfl_xor(pd[hh], m);
        }
      }
      if (n < NN) {
        if (c15 == 0) {
          *(float4*)(asrc + (size_t)n * 4) = make_float4(ps[0], ps[1], ps[2], ps[3]);
          *(float4*)(adst + (size_t)n * 4) = make_float4(pd[0], pd[1], pd[2], pd[3]);
        }
        __bf16* op = xsb + (size_t)n * HC + c15;
#pragma unroll
        for (int nt = 0; nt < 8; ++nt) op[nt * 16] = (__bf16)acc[mt * 8 + nt][r];
      }
    }
  }
}

// wave per node: fused score (leaky+exp) + aggregation + self-loop + residual relu.
// loff selects the layer's ae dwords inside the 8-dword record.
__global__ __launch_bounds__(256) void k_aggr(const int* __restrict__ row_ptr, const unsigned* __restrict__ recd,
                                              int loff, const __bf16* __restrict__ xsb,
                                              const float* __restrict__ asrc, const float* __restrict__ adst,
                                              const float* __restrict__ bgi, float* __restrict__ h) {
  int wid = (blockIdx.x * 256 + threadIdx.x) >> 6;
  if (wid >= NN) return;
  int lane = threadIdx.x & 63;
  int ch0 = 2 * lane, head = lane >> 4;
  int hs = head >> 1;
  int j0 = row_ptr[wid], j1 = row_ptr[wid + 1];
  float ad = adst[wid * 4 + head];
  float acc0 = 0.f, acc1 = 0.f, dsum = 0.f, aes = 0.f;
  int j = j0;
  for (; j + 8 <= j1; j += 8) {
    int ss[8];
    float av[8];
#pragma unroll
    for (int u = 0; u < 8; ++u) {
      const unsigned* rp = recd + (size_t)(j + u) * 8;
      ss[u] = (int)rp[0];
      unsigned aw = rp[loff + hs];
      av[u] = (head & 1) ? bhi(aw) : blo(aw);
    }
    float as[8];
    unsigned xv[8];
#pragma unroll
    for (int u = 0; u < 8; ++u) {
      as[u] = asrc[(size_t)ss[u] * 4 + head];
      xv[u] = *(const unsigned*)(xsb + (size_t)ss[u] * HC + ch0);
    }
#pragma unroll
    for (int u = 0; u < 8; ++u) {
      float a = as[u] + ad + av[u];
      a = a > 0.f ? a : NEGS * a;
      float e = __expf(a);
      acc0 += e * blo(xv[u]);
      acc1 += e * bhi(xv[u]);
      dsum += e;
      aes += av[u];
    }
  }
  for (; j < j1; ++j) {
    const unsigned* rp = recd + (size_t)j * 8;
    int s0 = (int)rp[0];
    unsigned aw = rp[loff + hs];
    float v0 = (head & 1) ? bhi(aw) : blo(aw);
    float as0 = asrc[(size_t)s0 * 4 + head];
    unsigned x0 = *(const unsigned*)(xsb + (size_t)s0 * HC + ch0);
    float a0 = as0 + ad + v0;
    a0 = a0 > 0.f ? a0 : NEGS * a0;
    float e0 = __expf(a0);
    acc0 += e0 * blo(x0);
    acc1 += e0 * bhi(x0);
    dsum += e0;
    aes += v0;
  }
  int deg = j1 - j0;
  float aself = (deg > 0) ? aes / (float)deg : 0.f;
  float al = asrc[wid * 4 + head] + ad + aself;
  al = al > 0.f ? al : NEGS * al;
  float exl = __expf(al);
  unsigned xv = *(const unsigned*)(xsb + (size_t)wid * HC + ch0);
  float inv = 1.f / (dsum + exl);
  float o0 = (acc0 + exl * blo(xv)) * inv;
  float o1 = (acc1 + exl * bhi(xv)) * inv;
  float* hp = h + (size_t)wid * HC;
  hp[ch0] += fmaxf(0.f, o0 + bgi[ch0]);
  hp[ch0 + 1] += fmaxf(0.f, o1 + bgi[ch0 + 1]);
}

__global__ __launch_bounds__(256) void k_emb(const float* __restrict__ h, float* __restrict__ emb) {
  int t = blockIdx.x * 256 + threadIdx.x;
  int stride = gridDim.x * 256;
  float s = 0.f;
  for (int i = t; i < NN * HC; i += stride) s += h[i];
  __shared__ float red[256];
  red[threadIdx.x] = s;
  __syncthreads();
  if (threadIdx.x < 128) {
    float v2 = red[threadIdx.x] + red[threadIdx.x + 128];
    atomicAdd(&emb[threadIdx.x], v2 * (1.f / NN));
  }
}

extern "C" void kernel_launch(void* const* d_in, const int* in_sizes, int n_in, void* d_out, int out_size,
                              void* d_ws, size_t ws_size, hipStream_t stream) {
  (void)in_sizes; (void)n_in; (void)out_size; (void)ws_size;
  const float* x = (const float*)d_in[0];
  const int* ei = (const int*)d_in[1];
  const float* ea = (const float*)d_in[2];
  const float* Wn = (const float*)d_in[3];
  const float* bn = (const float*)d_in[4];
  const float* We = (const float*)d_in[5];
  const float* be = (const float*)d_in[6];
  const float* lng = (const float*)d_in[7];
  const float* lnb = (const float*)d_in[8];
  const float* Wg = (const float*)d_in[9];
  const float* atts = (const float*)d_in[10];
  const float* attd = (const float*)d_in[11];
  const float* atte = (const float*)d_in[12];
  const float* Wed = (const float*)d_in[13];
  const float* bg = (const float*)d_in[14];
  float* h = (float*)d_out;
  float* emb = h + (size_t)NN * HC;

  char* w = (char*)d_ws;
  size_t off = 0;
  auto alloc = [&](size_t bytes) {
    void* p = w + off;
    off = (off + bytes + 255) & ~(size_t)255;
    return p;
  };
  __bf16* xsb = (__bf16*)alloc((size_t)NN * HC * 2);
  float* asrc = (float*)alloc((size_t)NN * 4 * 4);
  float* adst = (float*)alloc((size_t)NN * 4 * 4);
  int* cnt = (int*)alloc((size_t)NN * 4);
  int* row_ptr = (int*)alloc((size_t)(NN + 1) * 4);
  int* wr_ptr = (int*)alloc((size_t)NN * 4);
  int* bsum = (int*)alloc(256);
  int* stmp = (int*)alloc((size_t)NN * 4);
  uint4* rec = (uint4*)alloc((size_t)EE * 32);
  float* Pc = (float*)alloc(3 * 36 * 4);
  __bf16* wgt = (__bf16*)alloc((size_t)3 * 128 * 136 * 2);

  hipMemsetAsync(cnt, 0, (size_t)NN * 4, stream);
  hipMemsetAsync(emb, 0, HC * 4, stream);

  k_h0<<<cdiv(NN * HC, 256), 256, 0, stream>>>(x, Wn, bn, h);
  k_hist<<<cdiv(EE, 256), 256, 0, stream>>>(ei, cnt);
  int nb = cdiv(NN, 1024);
  k_scan1<<<nb, 1024, 0, stream>>>(cnt, stmp, bsum);
  k_scan2<<<1, 64, 0, stream>>>(bsum, nb);
  k_scan3<<<nb, 1024, 0, stream>>>(stmp, bsum, row_ptr, wr_ptr);
  k_wcoef<<<1, 128, 0, stream>>>(We, be, Wed, atte, Pc);
  k_prep<<<cdiv(3 * 128 * 136, 256), 256, 0, stream>>>(Wg, wgt);
  k_build<<<cdiv(EE, 256), 256, 0, stream>>>(ei, ea, Pc, wr_ptr, rec);

  for (int i = 0; i < 3; ++i) {
    k_node<<<cdiv(NN, 128), 256, 0, stream>>>(h, lng + i * HC, lnb + i * HC, wgt + (size_t)i * 128 * 136,
                                              atts + i * HC, attd + i * HC, xsb, asrc, adst);
    k_aggr<<<cdiv(NN, 4), 256, 0, stream>>>(row_ptr, (const unsigned*)rec, 1 + 2 * i, xsb, asrc, adst,
                                            bg + i * HC, h);
  }
  k_emb<<<512, 256, 0, stream>>>(h, emb);
}